// Round 1
// baseline (1158.480 us; speedup 1.0000x reference)
//
#include <hip/hip_runtime.h>
#include <hip/hip_bf16.h>

// Problem constants (match reference)
#define DD 128      // feature dim
#define AA 4        // edge attr dim
#define HH 2        // heads

// ---------------------------------------------------------------------------
// CSR build: histogram -> scan -> scatter (dst-sorted edge list)
// ---------------------------------------------------------------------------

__global__ void hist_kernel(const int* __restrict__ dst, int* __restrict__ cnt, int E) {
    int e = blockIdx.x * blockDim.x + threadIdx.x;
    if (e < E) atomicAdd(&cnt[dst[e]], 1);
}

__global__ __launch_bounds__(1024) void scan_kernel(const int* __restrict__ cnt,
                                                    int* __restrict__ row_off,
                                                    int* __restrict__ cursor, int N) {
    __shared__ int wsum[16];
    __shared__ int stot;
    int t = threadIdx.x;
    int lane = t & 63, wv = t >> 6;
    if (t == 0) stot = 0;
    __syncthreads();
    for (int base = 0; base < N; base += 1024) {
        int idx = base + t;
        int v = (idx < N) ? cnt[idx] : 0;
        // wave-level inclusive scan
        int x = v;
        #pragma unroll
        for (int o = 1; o < 64; o <<= 1) {
            int u = __shfl_up(x, o);
            if (lane >= o) x += u;
        }
        if (lane == 63) wsum[wv] = x;
        __syncthreads();
        int woff = 0;
        for (int i = 0; i < wv; ++i) woff += wsum[i];
        int incl = x + woff;
        int run = stot;
        __syncthreads();
        if (t == 1023) stot = run + incl;
        if (idx < N) {
            int ex = run + incl - v;
            row_off[idx] = ex;
            cursor[idx] = ex;
        }
        __syncthreads();
    }
    if (t == 0) row_off[N] = stot;
}

__global__ void scatter_kernel(const int* __restrict__ src, const int* __restrict__ dst,
                               int* __restrict__ cursor, int* __restrict__ csr_src,
                               int* __restrict__ pos_of_edge, int E) {
    int e = blockIdx.x * blockDim.x + threadIdx.x;
    if (e >= E) return;
    int p = atomicAdd(&cursor[dst[e]], 1);
    csr_src[p] = src[e];
    pos_of_edge[e] = p;
}

// ---------------------------------------------------------------------------
// Node GEMM: xh[N,256] = X[N,128] @ W[128,256] + bias
// 64x64 tile per 256-thread block, 4x4 register blocking per thread.
// ---------------------------------------------------------------------------

__global__ __launch_bounds__(256) void gemm_xh(const float* __restrict__ X,
                                               const float* __restrict__ W,
                                               const float* __restrict__ bias,
                                               float* __restrict__ Y, int N) {
    __shared__ __align__(16) float xs[64][68];   // [k][row], padded stride
    __shared__ __align__(16) float ws[64][64];   // [k][col]
    int br = blockIdx.x >> 2, bc = blockIdx.x & 3;
    int r0 = br * 64, c0 = bc * 64;
    int t = threadIdx.x;
    int lr = t >> 2, q = t & 3;
    int tc = (t & 15) * 4;
    int tr = (t >> 4) * 4;
    float acc[4][4] = {};

    for (int kt = 0; kt < 128; kt += 64) {
        int row = min(r0 + lr, N - 1);
        const float4* xrow = (const float4*)(X + (size_t)row * 128 + kt);
        const float4* wrow = (const float4*)(W + (size_t)(kt + lr) * 256 + c0);
        #pragma unroll
        for (int j = 0; j < 4; ++j) {
            int q4 = q + j * 4;          // float4 index 0..15 within 64 floats
            float4 v = xrow[q4];
            xs[q4 * 4 + 0][lr] = v.x;
            xs[q4 * 4 + 1][lr] = v.y;
            xs[q4 * 4 + 2][lr] = v.z;
            xs[q4 * 4 + 3][lr] = v.w;
            float4 wvv = wrow[q4];
            *(float4*)&ws[lr][q4 * 4] = wvv;
        }
        __syncthreads();
        #pragma unroll 8
        for (int k = 0; k < 64; ++k) {
            float4 a = *(const float4*)&xs[k][tr];
            float4 b = *(const float4*)&ws[k][tc];
            float av[4] = {a.x, a.y, a.z, a.w};
            float bv[4] = {b.x, b.y, b.z, b.w};
            #pragma unroll
            for (int i = 0; i < 4; ++i)
                #pragma unroll
                for (int j = 0; j < 4; ++j)
                    acc[i][j] += av[i] * bv[j];
        }
        __syncthreads();
    }

    float4 bv4 = *(const float4*)(bias + c0 + tc);
    #pragma unroll
    for (int i = 0; i < 4; ++i) {
        int row = r0 + tr + i;
        if (row < N) {
            float4 o;
            o.x = acc[i][0] + bv4.x;
            o.y = acc[i][1] + bv4.y;
            o.z = acc[i][2] + bv4.z;
            o.w = acc[i][3] + bv4.w;
            *(float4*)(Y + (size_t)row * 256 + c0 + tc) = o;
        }
    }
}

// ---------------------------------------------------------------------------
// Per-node attention logits: ai[n,h] = xh[n,h,:].att_src[h], aj analogous.
// One wave per node. aiaj layout: [N][4] = (ai0, ai1, aj0, aj1)
// ---------------------------------------------------------------------------

__global__ __launch_bounds__(256) void node_atts(const float* __restrict__ xh,
                                                 const float* __restrict__ att,
                                                 float* __restrict__ aiaj, int N) {
    int gt = blockIdx.x * blockDim.x + threadIdx.x;
    int wid = gt >> 6;
    int lane = threadIdx.x & 63;
    if (wid >= N) return;
    float4 xv = ((const float4*)xh)[(size_t)wid * 64 + lane];
    int head = lane >> 5;
    int dimbase = (lane & 31) * 4;
    const float* atth = att + head * (2 * DD + AA);
    float4 as = *(const float4*)(atth + dimbase);
    float4 ad = *(const float4*)(atth + DD + dimbase);
    float pi = xv.x * as.x + xv.y * as.y + xv.z * as.z + xv.w * as.w;
    float pj = xv.x * ad.x + xv.y * ad.y + xv.z * ad.z + xv.w * ad.w;
    #pragma unroll
    for (int o = 16; o; o >>= 1) {
        pi += __shfl_xor(pi, o);
        pj += __shfl_xor(pj, o);
    }
    float pi1 = __shfl(pi, 32);
    float pj1 = __shfl(pj, 32);
    if (lane == 0) {
        float4 r; r.x = pi; r.y = pi1; r.z = pj; r.w = pj1;
        ((float4*)aiaj)[wid] = r;
    }
}

// ---------------------------------------------------------------------------
// Edge transform: e_h = e_in @ linE (4->8), ae[e,h] = e_h . att_e[h],
// e_next = relu(mean_h e_h). ae written in CSR-permuted order.
// ---------------------------------------------------------------------------

__global__ void edge_kernel(const float* __restrict__ ein, const float* __restrict__ linE,
                            const float* __restrict__ att, const int* __restrict__ pos_of_edge,
                            float* __restrict__ enext, float* __restrict__ ae_perm, int E) {
    int e = blockIdx.x * blockDim.x + threadIdx.x;
    if (e >= E) return;
    float4 ev = ((const float4*)ein)[e];
    float eh[8];
    #pragma unroll
    for (int c = 0; c < 8; ++c)
        eh[c] = ev.x * linE[c] + ev.y * linE[8 + c] + ev.z * linE[16 + c] + ev.w * linE[24 + c];
    float ae0 = 0.f, ae1 = 0.f;
    #pragma unroll
    for (int a = 0; a < 4; ++a) {
        ae0 += eh[a]     * att[2 * DD + a];
        ae1 += eh[4 + a] * att[(2 * DD + AA) + 2 * DD + a];
    }
    int p = pos_of_edge[e];
    float2 aev; aev.x = ae0; aev.y = ae1;
    ((float2*)ae_perm)[p] = aev;
    float4 en;
    en.x = fmaxf(0.5f * (eh[0] + eh[4]), 0.f);
    en.y = fmaxf(0.5f * (eh[1] + eh[5]), 0.f);
    en.z = fmaxf(0.5f * (eh[2] + eh[6]), 0.f);
    en.w = fmaxf(0.5f * (eh[3] + eh[7]), 0.f);
    ((float4*)enext)[e] = en;
}

// ---------------------------------------------------------------------------
// Aggregation: one wave (64-thread block) per destination node.
// Segment softmax + weighted gather-sum of xh[src], skip, head-mean, relu.
// ---------------------------------------------------------------------------

__global__ __launch_bounds__(64) void aggregate(const float* __restrict__ xh,
                                                const float* __restrict__ aiaj,
                                                const float* __restrict__ ae,
                                                const int* __restrict__ row_off,
                                                const int* __restrict__ csr_src,
                                                float* __restrict__ hout, int N) {
    int d = blockIdx.x;
    int lane = threadIdx.x;
    int s0 = row_off[d], s1 = row_off[d + 1];
    int deg = s1 - s0;
    const float2* aiaj2 = (const float2*)aiaj;
    float2 ajv = aiaj2[d * 2 + 1];   // (aj0, aj1)

    // Phase A: segment max per head
    float mx0 = -1e30f, mx1 = -1e30f;
    for (int i = lane; i < deg; i += 64) {
        int s = csr_src[s0 + i];
        float2 aiv = aiaj2[s * 2];
        float2 aev = ((const float2*)ae)[s0 + i];
        float a0 = aiv.x + ajv.x + aev.x; a0 = a0 > 0.f ? a0 : 0.2f * a0;
        float a1 = aiv.y + ajv.y + aev.y; a1 = a1 > 0.f ? a1 : 0.2f * a1;
        mx0 = fmaxf(mx0, a0); mx1 = fmaxf(mx1, a1);
    }
    #pragma unroll
    for (int o = 32; o; o >>= 1) {
        mx0 = fmaxf(mx0, __shfl_xor(mx0, o));
        mx1 = fmaxf(mx1, __shfl_xor(mx1, o));
    }

    __shared__ float lex[64][2];
    __shared__ int lsrc[64];
    float4 acc = {0.f, 0.f, 0.f, 0.f};
    float den0 = 0.f, den1 = 0.f;
    int head = lane >> 5;

    for (int c = 0; c < deg; c += 64) {
        int n = min(64, deg - c);
        if (lane < n) {
            int p = s0 + c + lane;
            int s = csr_src[p];
            float2 aiv = aiaj2[s * 2];
            float2 aev = ((const float2*)ae)[p];
            float a0 = aiv.x + ajv.x + aev.x; a0 = a0 > 0.f ? a0 : 0.2f * a0;
            float a1 = aiv.y + ajv.y + aev.y; a1 = a1 > 0.f ? a1 : 0.2f * a1;
            float e0 = __expf(a0 - mx0), e1 = __expf(a1 - mx1);
            den0 += e0; den1 += e1;
            lex[lane][0] = e0; lex[lane][1] = e1;
            lsrc[lane] = s;
        }
        __syncthreads();
        #pragma unroll 4
        for (int j = 0; j < n; ++j) {
            float w = lex[j][head];
            float4 xv = ((const float4*)xh)[(size_t)lsrc[j] * 64 + lane];
            acc.x += w * xv.x; acc.y += w * xv.y;
            acc.z += w * xv.z; acc.w += w * xv.w;
        }
        __syncthreads();
    }

    #pragma unroll
    for (int o = 32; o; o >>= 1) {
        den0 += __shfl_xor(den0, o);
        den1 += __shfl_xor(den1, o);
    }
    float den = head ? den1 : den0;
    if (deg == 0) den = 1.0f;
    float inv = 1.0f / den;

    float4 xd = ((const float4*)xh)[(size_t)d * 64 + lane];
    float4 v;
    v.x = acc.x * inv + xd.x;
    v.y = acc.y * inv + xd.y;
    v.z = acc.z * inv + xd.z;
    v.w = acc.w * inv + xd.w;
    // head mean: partner lane is lane ^ 32 (same dim, other head)
    float4 o2;
    o2.x = __shfl_xor(v.x, 32);
    o2.y = __shfl_xor(v.y, 32);
    o2.z = __shfl_xor(v.z, 32);
    o2.w = __shfl_xor(v.w, 32);
    if (lane < 32) {
        float4 r;
        r.x = fmaxf(0.5f * (v.x + o2.x), 0.f);
        r.y = fmaxf(0.5f * (v.y + o2.y), 0.f);
        r.z = fmaxf(0.5f * (v.z + o2.z), 0.f);
        r.w = fmaxf(0.5f * (v.w + o2.w), 0.f);
        ((float4*)hout)[(size_t)d * 32 + lane] = r;
    }
}

// ---------------------------------------------------------------------------
// Final pooling: y[g] = fb + sum_{n in g} h[n,:] . fw
// ---------------------------------------------------------------------------

__global__ void init_y(float* __restrict__ y, const float* __restrict__ fb, int G) {
    int g = blockIdx.x * blockDim.x + threadIdx.x;
    if (g < G) y[g] = fb[0];
}

__global__ __launch_bounds__(256) void pool_kernel(const float* __restrict__ h,
                                                   const int* __restrict__ batch,
                                                   const float* __restrict__ fw,
                                                   float* __restrict__ y, int N) {
    int gt = blockIdx.x * blockDim.x + threadIdx.x;
    int wid = gt >> 6;
    int lane = threadIdx.x & 63;
    if (wid >= N) return;
    float2 hv = ((const float2*)h)[(size_t)wid * 64 + lane];
    float2 wv = ((const float2*)fw)[lane];
    float p = hv.x * wv.x + hv.y * wv.y;
    #pragma unroll
    for (int o = 32; o; o >>= 1) p += __shfl_xor(p, o);
    if (lane == 0) atomicAdd(&y[batch[wid]], p);
}

// ---------------------------------------------------------------------------
// Host side
// ---------------------------------------------------------------------------

extern "C" void kernel_launch(void* const* d_in, const int* in_sizes, int n_in,
                              void* d_out, int out_size, void* d_ws, size_t ws_size,
                              hipStream_t stream) {
    const float* x     = (const float*)d_in[0];
    const int*   ei    = (const int*)d_in[1];
    const float* eattr = (const float*)d_in[2];
    const int*   batch = (const int*)d_in[3];
    const float* fw    = (const float*)d_in[16];
    const float* fb    = (const float*)d_in[17];
    float* y = (float*)d_out;

    const int N = in_sizes[0] / DD;     // 50000
    const int E = in_sizes[1] / 2;      // 800000
    const int G = out_size;             // 128

    const int* src = ei;
    const int* dst = ei + E;

    // workspace carve-up (all offsets 256B aligned)
    char* ws = (char*)d_ws;
    size_t off = 0;
    auto carve = [&](size_t bytes) {
        char* p = ws + off;
        off += (bytes + 255) & ~(size_t)255;
        return p;
    };
    float* xh      = (float*)carve((size_t)N * 256 * 4);
    float* hA      = (float*)carve((size_t)N * 128 * 4);
    float* hB      = (float*)carve((size_t)N * 128 * 4);
    float* eA      = (float*)carve((size_t)E * 4 * 4);
    float* eB      = (float*)carve((size_t)E * 4 * 4);
    float* ae_perm = (float*)carve((size_t)E * 2 * 4);
    float* aiaj    = (float*)carve((size_t)N * 4 * 4);
    int*   row_off = (int*)carve((size_t)(N + 1) * 4);
    int*   cursor  = (int*)carve((size_t)N * 4);
    int*   cnt     = (int*)carve((size_t)N * 4);
    int*   csr_src = (int*)carve((size_t)E * 4);
    int*   pos     = (int*)carve((size_t)E * 4);

    // ---- CSR build (once per call; graph is layer-invariant) ----
    hipMemsetAsync(cnt, 0, (size_t)N * 4, stream);
    int eb = (E + 255) / 256;
    hist_kernel<<<eb, 256, 0, stream>>>(dst, cnt, E);
    scan_kernel<<<1, 1024, 0, stream>>>(cnt, row_off, cursor, N);
    scatter_kernel<<<eb, 256, 0, stream>>>(src, dst, cursor, csr_src, pos, E);

    // ---- 3 GAT layers ----
    const float* xin = x;
    const float* ein = eattr;
    int gemm_blocks = ((N + 63) / 64) * 4;
    int wave_blocks = (N * 64 + 255) / 256;

    for (int l = 0; l < 3; ++l) {
        const float* linN = (const float*)d_in[4 + 4 * l];
        const float* linE = (const float*)d_in[5 + 4 * l];
        const float* att  = (const float*)d_in[6 + 4 * l];
        const float* bias = (const float*)d_in[7 + 4 * l];
        float* hout = (l == 0) ? hA : (l == 1) ? hB : hA;
        float* eout = (l == 0) ? eA : (l == 1) ? eB : eA;

        gemm_xh<<<gemm_blocks, 256, 0, stream>>>(xin, linN, bias, xh, N);
        node_atts<<<wave_blocks, 256, 0, stream>>>(xh, att, aiaj, N);
        edge_kernel<<<eb, 256, 0, stream>>>(ein, linE, att, pos, eout, ae_perm, E);
        aggregate<<<N, 64, 0, stream>>>(xh, aiaj, ae_perm, row_off, csr_src, hout, N);

        xin = hout;
        ein = eout;
    }

    // ---- pooling + final linear ----
    init_y<<<1, 128, 0, stream>>>(y, fb, G);
    pool_kernel<<<wave_blocks, 256, 0, stream>>>(xin, batch, fw, y, N);
}

// Round 2
// 868.666 us; speedup vs baseline: 1.3336x; 1.3336x over previous
//
#include <hip/hip_runtime.h>
#include <hip/hip_bf16.h>

// Problem constants (match reference)
#define DD 128      // feature dim
#define AA 4        // edge attr dim
#define HH 2        // heads

// ---------------------------------------------------------------------------
// CSR build: histogram -> scan -> scatter (dst-sorted edge list)
// ---------------------------------------------------------------------------

__global__ void hist_kernel(const int* __restrict__ dst, int* __restrict__ cnt, int E) {
    int e = blockIdx.x * blockDim.x + threadIdx.x;
    if (e < E) atomicAdd(&cnt[dst[e]], 1);
}

__global__ __launch_bounds__(1024) void scan_kernel(const int* __restrict__ cnt,
                                                    int* __restrict__ row_off,
                                                    int* __restrict__ cursor, int N) {
    __shared__ int wsum[16];
    __shared__ int stot;
    int t = threadIdx.x;
    int lane = t & 63, wv = t >> 6;
    if (t == 0) stot = 0;
    __syncthreads();
    for (int base = 0; base < N; base += 1024) {
        int idx = base + t;
        int v = (idx < N) ? cnt[idx] : 0;
        // wave-level inclusive scan
        int x = v;
        #pragma unroll
        for (int o = 1; o < 64; o <<= 1) {
            int u = __shfl_up(x, o);
            if (lane >= o) x += u;
        }
        if (lane == 63) wsum[wv] = x;
        __syncthreads();
        int woff = 0;
        for (int i = 0; i < wv; ++i) woff += wsum[i];
        int incl = x + woff;
        int run = stot;
        __syncthreads();
        if (t == 1023) stot = run + incl;
        if (idx < N) {
            int ex = run + incl - v;
            row_off[idx] = ex;
            cursor[idx] = ex;
        }
        __syncthreads();
    }
    if (t == 0) row_off[N] = stot;
}

__global__ void scatter_kernel(const int* __restrict__ src, const int* __restrict__ dst,
                               int* __restrict__ cursor, int* __restrict__ csr_src,
                               int* __restrict__ pos_of_edge, int E) {
    int e = blockIdx.x * blockDim.x + threadIdx.x;
    if (e >= E) return;
    int p = atomicAdd(&cursor[dst[e]], 1);
    csr_src[p] = src[e];
    pos_of_edge[e] = p;
}

// ---------------------------------------------------------------------------
// Node GEMM: xh[N,256] = X[N,128] @ W[128,256] + bias
// 64x64 tile per 256-thread block, 4x4 register blocking per thread.
// ---------------------------------------------------------------------------

__global__ __launch_bounds__(256) void gemm_xh(const float* __restrict__ X,
                                               const float* __restrict__ W,
                                               const float* __restrict__ bias,
                                               float* __restrict__ Y, int N) {
    __shared__ __align__(16) float xs[64][68];   // [k][row], padded stride
    __shared__ __align__(16) float ws[64][64];   // [k][col]
    int br = blockIdx.x >> 2, bc = blockIdx.x & 3;
    int r0 = br * 64, c0 = bc * 64;
    int t = threadIdx.x;
    int lr = t >> 2, q = t & 3;
    int tc = (t & 15) * 4;
    int tr = (t >> 4) * 4;
    float acc[4][4] = {};

    for (int kt = 0; kt < 128; kt += 64) {
        int row = min(r0 + lr, N - 1);
        const float4* xrow = (const float4*)(X + (size_t)row * 128 + kt);
        const float4* wrow = (const float4*)(W + (size_t)(kt + lr) * 256 + c0);
        #pragma unroll
        for (int j = 0; j < 4; ++j) {
            int q4 = q + j * 4;          // float4 index 0..15 within 64 floats
            float4 v = xrow[q4];
            xs[q4 * 4 + 0][lr] = v.x;
            xs[q4 * 4 + 1][lr] = v.y;
            xs[q4 * 4 + 2][lr] = v.z;
            xs[q4 * 4 + 3][lr] = v.w;
            float4 wvv = wrow[q4];
            *(float4*)&ws[lr][q4 * 4] = wvv;
        }
        __syncthreads();
        #pragma unroll 8
        for (int k = 0; k < 64; ++k) {
            float4 a = *(const float4*)&xs[k][tr];
            float4 b = *(const float4*)&ws[k][tc];
            float av[4] = {a.x, a.y, a.z, a.w};
            float bv[4] = {b.x, b.y, b.z, b.w};
            #pragma unroll
            for (int i = 0; i < 4; ++i)
                #pragma unroll
                for (int j = 0; j < 4; ++j)
                    acc[i][j] += av[i] * bv[j];
        }
        __syncthreads();
    }

    float4 bv4 = *(const float4*)(bias + c0 + tc);
    #pragma unroll
    for (int i = 0; i < 4; ++i) {
        int row = r0 + tr + i;
        if (row < N) {
            float4 o;
            o.x = acc[i][0] + bv4.x;
            o.y = acc[i][1] + bv4.y;
            o.z = acc[i][2] + bv4.z;
            o.w = acc[i][3] + bv4.w;
            *(float4*)(Y + (size_t)row * 256 + c0 + tc) = o;
        }
    }
}

// ---------------------------------------------------------------------------
// Per-node attention logits: ai[n,h] = xh[n,h,:].att_src[h], aj analogous.
// One wave per node. aiaj layout: [N][4] = (ai0, ai1, aj0, aj1)
// ---------------------------------------------------------------------------

__global__ __launch_bounds__(256) void node_atts(const float* __restrict__ xh,
                                                 const float* __restrict__ att,
                                                 float* __restrict__ aiaj, int N) {
    int gt = blockIdx.x * blockDim.x + threadIdx.x;
    int wid = gt >> 6;
    int lane = threadIdx.x & 63;
    if (wid >= N) return;
    float4 xv = ((const float4*)xh)[(size_t)wid * 64 + lane];
    int head = lane >> 5;
    int dimbase = (lane & 31) * 4;
    const float* atth = att + head * (2 * DD + AA);
    float4 as = *(const float4*)(atth + dimbase);
    float4 ad = *(const float4*)(atth + DD + dimbase);
    float pi = xv.x * as.x + xv.y * as.y + xv.z * as.z + xv.w * as.w;
    float pj = xv.x * ad.x + xv.y * ad.y + xv.z * ad.z + xv.w * ad.w;
    #pragma unroll
    for (int o = 16; o; o >>= 1) {
        pi += __shfl_xor(pi, o);
        pj += __shfl_xor(pj, o);
    }
    float pi1 = __shfl(pi, 32);
    float pj1 = __shfl(pj, 32);
    if (lane == 0) {
        float4 r; r.x = pi; r.y = pi1; r.z = pj; r.w = pj1;
        ((float4*)aiaj)[wid] = r;
    }
}

// ---------------------------------------------------------------------------
// Edge transform: e_h = e_in @ linE (4->8), ae[e,h] = e_h . att_e[h],
// e_next = relu(mean_h e_h). ae written in CSR-permuted order.
// ---------------------------------------------------------------------------

__global__ void edge_kernel(const float* __restrict__ ein, const float* __restrict__ linE,
                            const float* __restrict__ att, const int* __restrict__ pos_of_edge,
                            float* __restrict__ enext, float* __restrict__ ae_perm, int E) {
    int e = blockIdx.x * blockDim.x + threadIdx.x;
    if (e >= E) return;
    float4 ev = ((const float4*)ein)[e];
    float eh[8];
    #pragma unroll
    for (int c = 0; c < 8; ++c)
        eh[c] = ev.x * linE[c] + ev.y * linE[8 + c] + ev.z * linE[16 + c] + ev.w * linE[24 + c];
    float ae0 = 0.f, ae1 = 0.f;
    #pragma unroll
    for (int a = 0; a < 4; ++a) {
        ae0 += eh[a]     * att[2 * DD + a];
        ae1 += eh[4 + a] * att[(2 * DD + AA) + 2 * DD + a];
    }
    int p = pos_of_edge[e];
    float2 aev; aev.x = ae0; aev.y = ae1;
    ((float2*)ae_perm)[p] = aev;
    float4 en;
    en.x = fmaxf(0.5f * (eh[0] + eh[4]), 0.f);
    en.y = fmaxf(0.5f * (eh[1] + eh[5]), 0.f);
    en.z = fmaxf(0.5f * (eh[2] + eh[6]), 0.f);
    en.w = fmaxf(0.5f * (eh[3] + eh[7]), 0.f);
    ((float4*)enext)[e] = en;
}

// ---------------------------------------------------------------------------
// Aggregation: one wave (64-thread block) per destination node.
// Segment softmax + weighted gather-sum of xh[src], skip, head-mean, relu.
// ---------------------------------------------------------------------------

__global__ __launch_bounds__(64) void aggregate(const float* __restrict__ xh,
                                                const float* __restrict__ aiaj,
                                                const float* __restrict__ ae,
                                                const int* __restrict__ row_off,
                                                const int* __restrict__ csr_src,
                                                float* __restrict__ hout, int N) {
    int d = blockIdx.x;
    int lane = threadIdx.x;
    int s0 = row_off[d], s1 = row_off[d + 1];
    int deg = s1 - s0;
    const float2* aiaj2 = (const float2*)aiaj;
    float2 ajv = aiaj2[d * 2 + 1];   // (aj0, aj1)

    // Phase A: segment max per head
    float mx0 = -1e30f, mx1 = -1e30f;
    for (int i = lane; i < deg; i += 64) {
        int s = csr_src[s0 + i];
        float2 aiv = aiaj2[s * 2];
        float2 aev = ((const float2*)ae)[s0 + i];
        float a0 = aiv.x + ajv.x + aev.x; a0 = a0 > 0.f ? a0 : 0.2f * a0;
        float a1 = aiv.y + ajv.y + aev.y; a1 = a1 > 0.f ? a1 : 0.2f * a1;
        mx0 = fmaxf(mx0, a0); mx1 = fmaxf(mx1, a1);
    }
    #pragma unroll
    for (int o = 32; o; o >>= 1) {
        mx0 = fmaxf(mx0, __shfl_xor(mx0, o));
        mx1 = fmaxf(mx1, __shfl_xor(mx1, o));
    }

    __shared__ float lex[64][2];
    __shared__ int lsrc[64];
    float4 acc = {0.f, 0.f, 0.f, 0.f};
    float den0 = 0.f, den1 = 0.f;
    int head = lane >> 5;

    for (int c = 0; c < deg; c += 64) {
        int n = min(64, deg - c);
        if (lane < n) {
            int p = s0 + c + lane;
            int s = csr_src[p];
            float2 aiv = aiaj2[s * 2];
            float2 aev = ((const float2*)ae)[p];
            float a0 = aiv.x + ajv.x + aev.x; a0 = a0 > 0.f ? a0 : 0.2f * a0;
            float a1 = aiv.y + ajv.y + aev.y; a1 = a1 > 0.f ? a1 : 0.2f * a1;
            float e0 = __expf(a0 - mx0), e1 = __expf(a1 - mx1);
            den0 += e0; den1 += e1;
            lex[lane][0] = e0; lex[lane][1] = e1;
            lsrc[lane] = s;
        }
        __syncthreads();
        #pragma unroll 4
        for (int j = 0; j < n; ++j) {
            float w = lex[j][head];
            float4 xv = ((const float4*)xh)[(size_t)lsrc[j] * 64 + lane];
            acc.x += w * xv.x; acc.y += w * xv.y;
            acc.z += w * xv.z; acc.w += w * xv.w;
        }
        __syncthreads();
    }

    #pragma unroll
    for (int o = 32; o; o >>= 1) {
        den0 += __shfl_xor(den0, o);
        den1 += __shfl_xor(den1, o);
    }
    float den = head ? den1 : den0;
    if (deg == 0) den = 1.0f;
    float inv = 1.0f / den;

    float4 xd = ((const float4*)xh)[(size_t)d * 64 + lane];
    float4 v;
    v.x = acc.x * inv + xd.x;
    v.y = acc.y * inv + xd.y;
    v.z = acc.z * inv + xd.z;
    v.w = acc.w * inv + xd.w;
    // head mean: partner lane is lane ^ 32 (same dim, other head)
    float4 o2;
    o2.x = __shfl_xor(v.x, 32);
    o2.y = __shfl_xor(v.y, 32);
    o2.z = __shfl_xor(v.z, 32);
    o2.w = __shfl_xor(v.w, 32);
    if (lane < 32) {
        float4 r;
        r.x = fmaxf(0.5f * (v.x + o2.x), 0.f);
        r.y = fmaxf(0.5f * (v.y + o2.y), 0.f);
        r.z = fmaxf(0.5f * (v.z + o2.z), 0.f);
        r.w = fmaxf(0.5f * (v.w + o2.w), 0.f);
        ((float4*)hout)[(size_t)d * 32 + lane] = r;
    }
}

// ---------------------------------------------------------------------------
// Final pooling, stage 1: p[n] = h[n,:] . fw   (one wave per node, no atomics)
// ---------------------------------------------------------------------------

__global__ __launch_bounds__(256) void dot_kernel(const float* __restrict__ h,
                                                  const float* __restrict__ fw,
                                                  float* __restrict__ p, int N) {
    int gt = blockIdx.x * blockDim.x + threadIdx.x;
    int wid = gt >> 6;
    int lane = threadIdx.x & 63;
    if (wid >= N) return;
    float2 hv = ((const float2*)h)[(size_t)wid * 64 + lane];
    float2 wv = ((const float2*)fw)[lane];
    float s = hv.x * wv.x + hv.y * wv.y;
    #pragma unroll
    for (int o = 32; o; o >>= 1) s += __shfl_xor(s, o);
    if (lane == 0) p[wid] = s;
}

// ---------------------------------------------------------------------------
// Final pooling, stage 2: y[g] = fb + segment_sum(p, batch).
// batch is SORTED. 128 blocks over contiguous node ranges; per-thread
// register run-accumulation keyed on batch id, flush to LDS bins on key
// change, one global atomic per nonzero bin per block.
// ---------------------------------------------------------------------------

__global__ __launch_bounds__(256) void segpool_kernel(const float* __restrict__ p,
                                                      const int* __restrict__ batch,
                                                      float* __restrict__ y, int N, int G) {
    __shared__ float bins[128];
    int t = threadIdx.x;
    if (t < G) bins[t] = 0.f;
    __syncthreads();
    int per = (N + gridDim.x - 1) / gridDim.x;
    int lo = blockIdx.x * per;
    int hi = min(lo + per, N);
    float acc = 0.f;
    int key = -1;
    for (int i = lo + t; i < hi; i += 256) {
        int k = batch[i];
        float v = p[i];
        if (k != key) {
            if (key >= 0) atomicAdd(&bins[key], acc);
            key = k;
            acc = 0.f;
        }
        acc += v;
    }
    if (key >= 0) atomicAdd(&bins[key], acc);
    __syncthreads();
    if (t < G && bins[t] != 0.f) atomicAdd(&y[t], bins[t]);
}

__global__ void init_y(float* __restrict__ y, const float* __restrict__ fb, int G) {
    int g = blockIdx.x * blockDim.x + threadIdx.x;
    if (g < G) y[g] = fb[0];
}

// ---------------------------------------------------------------------------
// Host side
// ---------------------------------------------------------------------------

extern "C" void kernel_launch(void* const* d_in, const int* in_sizes, int n_in,
                              void* d_out, int out_size, void* d_ws, size_t ws_size,
                              hipStream_t stream) {
    const float* x     = (const float*)d_in[0];
    const int*   ei    = (const int*)d_in[1];
    const float* eattr = (const float*)d_in[2];
    const int*   batch = (const int*)d_in[3];
    const float* fw    = (const float*)d_in[16];
    const float* fb    = (const float*)d_in[17];
    float* y = (float*)d_out;

    const int N = in_sizes[0] / DD;     // 50000
    const int E = in_sizes[1] / 2;      // 800000
    const int G = out_size;             // 128

    const int* src = ei;
    const int* dst = ei + E;

    // workspace carve-up (all offsets 256B aligned)
    char* ws = (char*)d_ws;
    size_t off = 0;
    auto carve = [&](size_t bytes) {
        char* p = ws + off;
        off += (bytes + 255) & ~(size_t)255;
        return p;
    };
    float* xh      = (float*)carve((size_t)N * 256 * 4);
    float* hA      = (float*)carve((size_t)N * 128 * 4);
    float* hB      = (float*)carve((size_t)N * 128 * 4);
    float* eA      = (float*)carve((size_t)E * 4 * 4);
    float* eB      = (float*)carve((size_t)E * 4 * 4);
    float* ae_perm = (float*)carve((size_t)E * 2 * 4);
    float* aiaj    = (float*)carve((size_t)N * 4 * 4);
    int*   row_off = (int*)carve((size_t)(N + 1) * 4);
    int*   cursor  = (int*)carve((size_t)N * 4);
    int*   cnt     = (int*)carve((size_t)N * 4);
    int*   csr_src = (int*)carve((size_t)E * 4);
    int*   pos     = (int*)carve((size_t)E * 4);
    float* pdots   = (float*)carve((size_t)N * 4);

    // ---- CSR build (once per call; graph is layer-invariant) ----
    hipMemsetAsync(cnt, 0, (size_t)N * 4, stream);
    int eb = (E + 255) / 256;
    hist_kernel<<<eb, 256, 0, stream>>>(dst, cnt, E);
    scan_kernel<<<1, 1024, 0, stream>>>(cnt, row_off, cursor, N);
    scatter_kernel<<<eb, 256, 0, stream>>>(src, dst, cursor, csr_src, pos, E);

    // ---- 3 GAT layers ----
    const float* xin = x;
    const float* ein = eattr;
    int gemm_blocks = ((N + 63) / 64) * 4;
    int wave_blocks = (N * 64 + 255) / 256;

    for (int l = 0; l < 3; ++l) {
        const float* linN = (const float*)d_in[4 + 4 * l];
        const float* linE = (const float*)d_in[5 + 4 * l];
        const float* att  = (const float*)d_in[6 + 4 * l];
        const float* bias = (const float*)d_in[7 + 4 * l];
        float* hout = (l == 0) ? hA : (l == 1) ? hB : hA;
        float* eout = (l == 0) ? eA : (l == 1) ? eB : eA;

        gemm_xh<<<gemm_blocks, 256, 0, stream>>>(xin, linN, bias, xh, N);
        node_atts<<<wave_blocks, 256, 0, stream>>>(xh, att, aiaj, N);
        edge_kernel<<<eb, 256, 0, stream>>>(ein, linE, att, pos, eout, ae_perm, E);
        aggregate<<<N, 64, 0, stream>>>(xh, aiaj, ae_perm, row_off, csr_src, hout, N);

        xin = hout;
        ein = eout;
    }

    // ---- pooling + final linear (two-stage, contention-free) ----
    init_y<<<1, 128, 0, stream>>>(y, fb, G);
    dot_kernel<<<wave_blocks, 256, 0, stream>>>(xin, fw, pdots, N);
    segpool_kernel<<<128, 256, 0, stream>>>(pdots, batch, y, N, G);
}

// Round 3
// 687.000 us; speedup vs baseline: 1.6863x; 1.2644x over previous
//
#include <hip/hip_runtime.h>
#include <hip/hip_bf16.h>

// Problem constants (match reference)
#define DD 128      // feature dim
#define AA 4        // edge attr dim
#define HH 2        // heads

// bf16 pack/unpack (RNE, no NaN special-casing needed for this data)
__device__ inline unsigned short f2bf(float f) {
    unsigned u = __float_as_uint(f);
    unsigned r = (u + 0x7fffu + ((u >> 16) & 1u)) >> 16;
    return (unsigned short)r;
}
__device__ inline float4 unpack_bf16x4(uint2 v) {
    float4 r;
    r.x = __uint_as_float(v.x << 16);
    r.y = __uint_as_float(v.x & 0xffff0000u);
    r.z = __uint_as_float(v.y << 16);
    r.w = __uint_as_float(v.y & 0xffff0000u);
    return r;
}

// ---------------------------------------------------------------------------
// CSR build: histogram -> scan -> scatter (dst-sorted edge list)
// ---------------------------------------------------------------------------

__global__ void hist_kernel(const int* __restrict__ dst, int* __restrict__ cnt, int E) {
    int e = blockIdx.x * blockDim.x + threadIdx.x;
    if (e < E) atomicAdd(&cnt[dst[e]], 1);
}

__global__ __launch_bounds__(1024) void scan_kernel(const int* __restrict__ cnt,
                                                    int* __restrict__ row_off,
                                                    int* __restrict__ cursor, int N) {
    __shared__ int wsum[16];
    __shared__ int stot;
    int t = threadIdx.x;
    int lane = t & 63, wv = t >> 6;
    if (t == 0) stot = 0;
    __syncthreads();
    for (int base = 0; base < N; base += 1024) {
        int idx = base + t;
        int v = (idx < N) ? cnt[idx] : 0;
        int x = v;
        #pragma unroll
        for (int o = 1; o < 64; o <<= 1) {
            int u = __shfl_up(x, o);
            if (lane >= o) x += u;
        }
        if (lane == 63) wsum[wv] = x;
        __syncthreads();
        int woff = 0;
        for (int i = 0; i < wv; ++i) woff += wsum[i];
        int incl = x + woff;
        int run = stot;
        __syncthreads();
        if (t == 1023) stot = run + incl;
        if (idx < N) {
            int ex = run + incl - v;
            row_off[idx] = ex;
            cursor[idx] = ex;
        }
        __syncthreads();
    }
    if (t == 0) row_off[N] = stot;
}

__global__ void scatter_kernel(const int* __restrict__ src, const int* __restrict__ dst,
                               int* __restrict__ cursor, int* __restrict__ csr_src,
                               int* __restrict__ pos_of_edge, int E) {
    int e = blockIdx.x * blockDim.x + threadIdx.x;
    if (e >= E) return;
    int p = atomicAdd(&cursor[dst[e]], 1);
    csr_src[p] = src[e];
    pos_of_edge[e] = p;
}

// ---------------------------------------------------------------------------
// Node GEMM: xh[N,256] = X[N,128] @ W[128,256] + bias  (fp32 + bf16 copy)
// ---------------------------------------------------------------------------

__global__ __launch_bounds__(256) void gemm_xh(const float* __restrict__ X,
                                               const float* __restrict__ W,
                                               const float* __restrict__ bias,
                                               float* __restrict__ Y,
                                               uint2* __restrict__ Yb, int N) {
    __shared__ __align__(16) float xs[64][68];   // [k][row], padded stride
    __shared__ __align__(16) float ws[64][64];   // [k][col]
    int br = blockIdx.x >> 2, bc = blockIdx.x & 3;
    int r0 = br * 64, c0 = bc * 64;
    int t = threadIdx.x;
    int lr = t >> 2, q = t & 3;
    int tc = (t & 15) * 4;
    int tr = (t >> 4) * 4;
    float acc[4][4] = {};

    for (int kt = 0; kt < 128; kt += 64) {
        int row = min(r0 + lr, N - 1);
        const float4* xrow = (const float4*)(X + (size_t)row * 128 + kt);
        const float4* wrow = (const float4*)(W + (size_t)(kt + lr) * 256 + c0);
        #pragma unroll
        for (int j = 0; j < 4; ++j) {
            int q4 = q + j * 4;
            float4 v = xrow[q4];
            xs[q4 * 4 + 0][lr] = v.x;
            xs[q4 * 4 + 1][lr] = v.y;
            xs[q4 * 4 + 2][lr] = v.z;
            xs[q4 * 4 + 3][lr] = v.w;
            float4 wvv = wrow[q4];
            *(float4*)&ws[lr][q4 * 4] = wvv;
        }
        __syncthreads();
        #pragma unroll 8
        for (int k = 0; k < 64; ++k) {
            float4 a = *(const float4*)&xs[k][tr];
            float4 b = *(const float4*)&ws[k][tc];
            float av[4] = {a.x, a.y, a.z, a.w};
            float bv[4] = {b.x, b.y, b.z, b.w};
            #pragma unroll
            for (int i = 0; i < 4; ++i)
                #pragma unroll
                for (int j = 0; j < 4; ++j)
                    acc[i][j] += av[i] * bv[j];
        }
        __syncthreads();
    }

    float4 bv4 = *(const float4*)(bias + c0 + tc);
    #pragma unroll
    for (int i = 0; i < 4; ++i) {
        int row = r0 + tr + i;
        if (row < N) {
            float4 o;
            o.x = acc[i][0] + bv4.x;
            o.y = acc[i][1] + bv4.y;
            o.z = acc[i][2] + bv4.z;
            o.w = acc[i][3] + bv4.w;
            *(float4*)(Y + (size_t)row * 256 + c0 + tc) = o;
            uint2 pk;
            pk.x = (unsigned)f2bf(o.x) | ((unsigned)f2bf(o.y) << 16);
            pk.y = (unsigned)f2bf(o.z) | ((unsigned)f2bf(o.w) << 16);
            Yb[(size_t)row * 64 + ((c0 + tc) >> 2)] = pk;
        }
    }
}

// ---------------------------------------------------------------------------
// Per-node attention logits: ai[n,h] = xh[n,h,:].att_src[h], aj analogous.
// ---------------------------------------------------------------------------

__global__ __launch_bounds__(256) void node_atts(const float* __restrict__ xh,
                                                 const float* __restrict__ att,
                                                 float* __restrict__ aiaj, int N) {
    int gt = blockIdx.x * blockDim.x + threadIdx.x;
    int wid = gt >> 6;
    int lane = threadIdx.x & 63;
    if (wid >= N) return;
    float4 xv = ((const float4*)xh)[(size_t)wid * 64 + lane];
    int head = lane >> 5;
    int dimbase = (lane & 31) * 4;
    const float* atth = att + head * (2 * DD + AA);
    float4 as = *(const float4*)(atth + dimbase);
    float4 ad = *(const float4*)(atth + DD + dimbase);
    float pi = xv.x * as.x + xv.y * as.y + xv.z * as.z + xv.w * as.w;
    float pj = xv.x * ad.x + xv.y * ad.y + xv.z * ad.z + xv.w * ad.w;
    #pragma unroll
    for (int o = 16; o; o >>= 1) {
        pi += __shfl_xor(pi, o);
        pj += __shfl_xor(pj, o);
    }
    float pi1 = __shfl(pi, 32);
    float pj1 = __shfl(pj, 32);
    if (lane == 0) {
        float4 r; r.x = pi; r.y = pi1; r.z = pj; r.w = pj1;
        ((float4*)aiaj)[wid] = r;
    }
}

// ---------------------------------------------------------------------------
// Edge transform
// ---------------------------------------------------------------------------

__global__ void edge_kernel(const float* __restrict__ ein, const float* __restrict__ linE,
                            const float* __restrict__ att, const int* __restrict__ pos_of_edge,
                            float* __restrict__ enext, float* __restrict__ ae_perm, int E) {
    int e = blockIdx.x * blockDim.x + threadIdx.x;
    if (e >= E) return;
    float4 ev = ((const float4*)ein)[e];
    float eh[8];
    #pragma unroll
    for (int c = 0; c < 8; ++c)
        eh[c] = ev.x * linE[c] + ev.y * linE[8 + c] + ev.z * linE[16 + c] + ev.w * linE[24 + c];
    float ae0 = 0.f, ae1 = 0.f;
    #pragma unroll
    for (int a = 0; a < 4; ++a) {
        ae0 += eh[a]     * att[2 * DD + a];
        ae1 += eh[4 + a] * att[(2 * DD + AA) + 2 * DD + a];
    }
    int p = pos_of_edge[e];
    float2 aev; aev.x = ae0; aev.y = ae1;
    ((float2*)ae_perm)[p] = aev;
    float4 en;
    en.x = fmaxf(0.5f * (eh[0] + eh[4]), 0.f);
    en.y = fmaxf(0.5f * (eh[1] + eh[5]), 0.f);
    en.z = fmaxf(0.5f * (eh[2] + eh[6]), 0.f);
    en.w = fmaxf(0.5f * (eh[3] + eh[7]), 0.f);
    ((float4*)enext)[e] = en;
}

// ---------------------------------------------------------------------------
// Aggregation: one wave per dst node; bf16 gather payload (uint2 = 4 bf16).
// ---------------------------------------------------------------------------

__global__ __launch_bounds__(64) void aggregate(const float* __restrict__ xh,
                                                const uint2* __restrict__ xhb,
                                                const float* __restrict__ aiaj,
                                                const float* __restrict__ ae,
                                                const int* __restrict__ row_off,
                                                const int* __restrict__ csr_src,
                                                float* __restrict__ hout, int N) {
    int d = blockIdx.x;
    int lane = threadIdx.x;
    int s0 = row_off[d], s1 = row_off[d + 1];
    int deg = s1 - s0;
    const float2* aiaj2 = (const float2*)aiaj;
    float2 ajv = aiaj2[d * 2 + 1];   // (aj0, aj1)

    // Phase A: segment max per head
    float mx0 = -1e30f, mx1 = -1e30f;
    for (int i = lane; i < deg; i += 64) {
        int s = csr_src[s0 + i];
        float2 aiv = aiaj2[s * 2];
        float2 aev = ((const float2*)ae)[s0 + i];
        float a0 = aiv.x + ajv.x + aev.x; a0 = a0 > 0.f ? a0 : 0.2f * a0;
        float a1 = aiv.y + ajv.y + aev.y; a1 = a1 > 0.f ? a1 : 0.2f * a1;
        mx0 = fmaxf(mx0, a0); mx1 = fmaxf(mx1, a1);
    }
    #pragma unroll
    for (int o = 32; o; o >>= 1) {
        mx0 = fmaxf(mx0, __shfl_xor(mx0, o));
        mx1 = fmaxf(mx1, __shfl_xor(mx1, o));
    }

    __shared__ float lex[64][2];
    __shared__ int lsrc[64];
    float4 acc = {0.f, 0.f, 0.f, 0.f};
    float den0 = 0.f, den1 = 0.f;
    int head = lane >> 5;

    for (int c = 0; c < deg; c += 64) {
        int n = min(64, deg - c);
        if (lane < n) {
            int p = s0 + c + lane;
            int s = csr_src[p];
            float2 aiv = aiaj2[s * 2];
            float2 aev = ((const float2*)ae)[p];
            float a0 = aiv.x + ajv.x + aev.x; a0 = a0 > 0.f ? a0 : 0.2f * a0;
            float a1 = aiv.y + ajv.y + aev.y; a1 = a1 > 0.f ? a1 : 0.2f * a1;
            float e0 = __expf(a0 - mx0), e1 = __expf(a1 - mx1);
            den0 += e0; den1 += e1;
            lex[lane][0] = e0; lex[lane][1] = e1;
            lsrc[lane] = s;
        }
        __syncthreads();
        #pragma unroll 4
        for (int j = 0; j < n; ++j) {
            float w = lex[j][head];
            float4 xv = unpack_bf16x4(xhb[(size_t)lsrc[j] * 64 + lane]);
            acc.x += w * xv.x; acc.y += w * xv.y;
            acc.z += w * xv.z; acc.w += w * xv.w;
        }
        __syncthreads();
    }

    #pragma unroll
    for (int o = 32; o; o >>= 1) {
        den0 += __shfl_xor(den0, o);
        den1 += __shfl_xor(den1, o);
    }
    float den = head ? den1 : den0;
    if (deg == 0) den = 1.0f;
    float inv = 1.0f / den;

    float4 xd = ((const float4*)xh)[(size_t)d * 64 + lane];
    float4 v;
    v.x = acc.x * inv + xd.x;
    v.y = acc.y * inv + xd.y;
    v.z = acc.z * inv + xd.z;
    v.w = acc.w * inv + xd.w;
    float4 o2;
    o2.x = __shfl_xor(v.x, 32);
    o2.y = __shfl_xor(v.y, 32);
    o2.z = __shfl_xor(v.z, 32);
    o2.w = __shfl_xor(v.w, 32);
    if (lane < 32) {
        float4 r;
        r.x = fmaxf(0.5f * (v.x + o2.x), 0.f);
        r.y = fmaxf(0.5f * (v.y + o2.y), 0.f);
        r.z = fmaxf(0.5f * (v.z + o2.z), 0.f);
        r.w = fmaxf(0.5f * (v.w + o2.w), 0.f);
        ((float4*)hout)[(size_t)d * 32 + lane] = r;
    }
}

// ---------------------------------------------------------------------------
// Final pooling (two-stage, contention-free)
// ---------------------------------------------------------------------------

__global__ __launch_bounds__(256) void dot_kernel(const float* __restrict__ h,
                                                  const float* __restrict__ fw,
                                                  float* __restrict__ p, int N) {
    int gt = blockIdx.x * blockDim.x + threadIdx.x;
    int wid = gt >> 6;
    int lane = threadIdx.x & 63;
    if (wid >= N) return;
    float2 hv = ((const float2*)h)[(size_t)wid * 64 + lane];
    float2 wv = ((const float2*)fw)[lane];
    float s = hv.x * wv.x + hv.y * wv.y;
    #pragma unroll
    for (int o = 32; o; o >>= 1) s += __shfl_xor(s, o);
    if (lane == 0) p[wid] = s;
}

__global__ __launch_bounds__(256) void segpool_kernel(const float* __restrict__ p,
                                                      const int* __restrict__ batch,
                                                      float* __restrict__ y, int N, int G) {
    __shared__ float bins[128];
    int t = threadIdx.x;
    if (t < G) bins[t] = 0.f;
    __syncthreads();
    int per = (N + gridDim.x - 1) / gridDim.x;
    int lo = blockIdx.x * per;
    int hi = min(lo + per, N);
    float acc = 0.f;
    int key = -1;
    for (int i = lo + t; i < hi; i += 256) {
        int k = batch[i];
        float v = p[i];
        if (k != key) {
            if (key >= 0) atomicAdd(&bins[key], acc);
            key = k;
            acc = 0.f;
        }
        acc += v;
    }
    if (key >= 0) atomicAdd(&bins[key], acc);
    __syncthreads();
    if (t < G && bins[t] != 0.f) atomicAdd(&y[t], bins[t]);
}

__global__ void init_y(float* __restrict__ y, const float* __restrict__ fb, int G) {
    int g = blockIdx.x * blockDim.x + threadIdx.x;
    if (g < G) y[g] = fb[0];
}

// ---------------------------------------------------------------------------
// Host side
// ---------------------------------------------------------------------------

extern "C" void kernel_launch(void* const* d_in, const int* in_sizes, int n_in,
                              void* d_out, int out_size, void* d_ws, size_t ws_size,
                              hipStream_t stream) {
    const float* x     = (const float*)d_in[0];
    const int*   ei    = (const int*)d_in[1];
    const float* eattr = (const float*)d_in[2];
    const int*   batch = (const int*)d_in[3];
    const float* fw    = (const float*)d_in[16];
    const float* fb    = (const float*)d_in[17];
    float* y = (float*)d_out;

    const int N = in_sizes[0] / DD;     // 50000
    const int E = in_sizes[1] / 2;      // 800000
    const int G = out_size;             // 128

    const int* src = ei;
    const int* dst = ei + E;

    char* ws = (char*)d_ws;
    size_t off = 0;
    auto carve = [&](size_t bytes) {
        char* p = ws + off;
        off += (bytes + 255) & ~(size_t)255;
        return p;
    };
    float* xh      = (float*)carve((size_t)N * 256 * 4);
    uint2* xhb     = (uint2*)carve((size_t)N * 256 * 2);   // bf16 copy
    float* hA      = (float*)carve((size_t)N * 128 * 4);
    float* hB      = (float*)carve((size_t)N * 128 * 4);
    float* eA      = (float*)carve((size_t)E * 4 * 4);
    float* eB      = (float*)carve((size_t)E * 4 * 4);
    float* ae_perm = (float*)carve((size_t)E * 2 * 4);
    float* aiaj    = (float*)carve((size_t)N * 4 * 4);
    int*   row_off = (int*)carve((size_t)(N + 1) * 4);
    int*   cursor  = (int*)carve((size_t)N * 4);
    int*   cnt     = (int*)carve((size_t)N * 4);
    int*   csr_src = (int*)carve((size_t)E * 4);
    int*   pos     = (int*)carve((size_t)E * 4);
    float* pdots   = (float*)carve((size_t)N * 4);

    // ---- CSR build ----
    hipMemsetAsync(cnt, 0, (size_t)N * 4, stream);
    int eb = (E + 255) / 256;
    hist_kernel<<<eb, 256, 0, stream>>>(dst, cnt, E);
    scan_kernel<<<1, 1024, 0, stream>>>(cnt, row_off, cursor, N);
    scatter_kernel<<<eb, 256, 0, stream>>>(src, dst, cursor, csr_src, pos, E);

    // ---- 3 GAT layers ----
    const float* xin = x;
    const float* ein = eattr;
    int gemm_blocks = ((N + 63) / 64) * 4;
    int wave_blocks = (N * 64 + 255) / 256;

    for (int l = 0; l < 3; ++l) {
        const float* linN = (const float*)d_in[4 + 4 * l];
        const float* linE = (const float*)d_in[5 + 4 * l];
        const float* att  = (const float*)d_in[6 + 4 * l];
        const float* bias = (const float*)d_in[7 + 4 * l];
        float* hout = (l == 0) ? hA : (l == 1) ? hB : hA;
        float* eout = (l == 0) ? eA : (l == 1) ? eB : eA;

        gemm_xh<<<gemm_blocks, 256, 0, stream>>>(xin, linN, bias, xh, xhb, N);
        node_atts<<<wave_blocks, 256, 0, stream>>>(xh, att, aiaj, N);
        edge_kernel<<<eb, 256, 0, stream>>>(ein, linE, att, pos, eout, ae_perm, E);
        aggregate<<<N, 64, 0, stream>>>(xh, xhb, aiaj, ae_perm, row_off, csr_src, hout, N);

        xin = hout;
        ein = eout;
    }

    // ---- pooling + final linear ----
    init_y<<<1, 128, 0, stream>>>(y, fb, G);
    dot_kernel<<<wave_blocks, 256, 0, stream>>>(xin, fw, pdots, N);
    segpool_kernel<<<128, 256, 0, stream>>>(pdots, batch, y, N, G);
}

// Round 4
// 626.632 us; speedup vs baseline: 1.8487x; 1.0963x over previous
//
#include <hip/hip_runtime.h>
#include <hip/hip_bf16.h>

// Problem constants (match reference)
#define DD 128      // feature dim
#define AA 4        // edge attr dim
#define HH 2        // heads

// bf16 pack/unpack (RNE)
__device__ inline unsigned short f2bf(float f) {
    unsigned u = __float_as_uint(f);
    unsigned r = (u + 0x7fffu + ((u >> 16) & 1u)) >> 16;
    return (unsigned short)r;
}
__device__ inline float4 unpack_bf16x4(uint2 v) {
    float4 r;
    r.x = __uint_as_float(v.x << 16);
    r.y = __uint_as_float(v.x & 0xffff0000u);
    r.z = __uint_as_float(v.y << 16);
    r.w = __uint_as_float(v.y & 0xffff0000u);
    return r;
}

// ---------------------------------------------------------------------------
// CSR build: histogram -> 3-kernel parallel scan -> scatter
// ---------------------------------------------------------------------------

__global__ void hist_kernel(const int* __restrict__ dst, int* __restrict__ cnt, int E) {
    int e = blockIdx.x * blockDim.x + threadIdx.x;
    if (e < E) atomicAdd(&cnt[dst[e]], 1);
}

// scan1: per-1024-chunk sums
__global__ __launch_bounds__(256) void scan1(const int* __restrict__ cnt,
                                             int* __restrict__ bsum, int N) {
    __shared__ int wsh[4];
    int b = blockIdx.x, t = threadIdx.x;
    int lane = t & 63, w = t >> 6;
    int base = b * 1024;
    int v = 0;
    #pragma unroll
    for (int i = 0; i < 4; ++i) {
        int idx = base + i * 256 + t;
        v += (idx < N) ? cnt[idx] : 0;
    }
    #pragma unroll
    for (int o = 32; o; o >>= 1) v += __shfl_xor(v, o);
    if (lane == 0) wsh[w] = v;
    __syncthreads();
    if (t == 0) bsum[b] = wsh[0] + wsh[1] + wsh[2] + wsh[3];
}

// scan2: single-wave exclusive scan of chunk sums (NB <= 64)
__global__ __launch_bounds__(64) void scan2(int* __restrict__ bsum, int NB,
                                            int* __restrict__ total) {
    int t = threadIdx.x;
    int v = (t < NB) ? bsum[t] : 0;
    int x = v;
    #pragma unroll
    for (int o = 1; o < 64; o <<= 1) {
        int u = __shfl_up(x, o);
        if (t >= o) x += u;
    }
    if (t < NB) bsum[t] = x - v;      // exclusive prefix
    if (t == 63) *total = x;          // grand total -> row_off[N]
}

// scan3: final per-element exclusive prefix (chunk-local scan + chunk offset)
__global__ __launch_bounds__(256) void scan3(const int* __restrict__ cnt,
                                             const int* __restrict__ bsum,
                                             int* __restrict__ row_off,
                                             int* __restrict__ cursor, int N) {
    __shared__ int wtot[4];
    __shared__ int carry;
    int b = blockIdx.x, t = threadIdx.x;
    int lane = t & 63, w = t >> 6;
    if (t == 0) carry = bsum[b];
    __syncthreads();
    int base = b * 1024;
    #pragma unroll
    for (int it = 0; it < 4; ++it) {
        int idx = base + it * 256 + t;
        int v = (idx < N) ? cnt[idx] : 0;
        int x = v;
        #pragma unroll
        for (int o = 1; o < 64; o <<= 1) {
            int u = __shfl_up(x, o);
            if (lane >= o) x += u;
        }
        if (lane == 63) wtot[w] = x;
        __syncthreads();
        int woff = 0;
        for (int i = 0; i < w; ++i) woff += wtot[i];
        int c = carry;
        __syncthreads();
        if (t == 255) carry = c + woff + x;
        int ex = c + woff + x - v;
        if (idx < N) { row_off[idx] = ex; cursor[idx] = ex; }
        __syncthreads();
    }
}

__global__ void scatter_kernel(const int* __restrict__ src, const int* __restrict__ dst,
                               int* __restrict__ cursor, int* __restrict__ csr_src,
                               int* __restrict__ pos_of_edge, int E) {
    int e = blockIdx.x * blockDim.x + threadIdx.x;
    if (e >= E) return;
    int p = atomicAdd(&cursor[dst[e]], 1);
    csr_src[p] = src[e];
    pos_of_edge[e] = p;
}

// ---------------------------------------------------------------------------
// Node GEMM: xh[N,256] = X[N,128] @ W[128,256] + bias  (fp32 + bf16 copy)
// ---------------------------------------------------------------------------

__global__ __launch_bounds__(256) void gemm_xh(const float* __restrict__ X,
                                               const float* __restrict__ W,
                                               const float* __restrict__ bias,
                                               float* __restrict__ Y,
                                               uint2* __restrict__ Yb, int N) {
    __shared__ __align__(16) float xs[64][68];   // [k][row], padded stride
    __shared__ __align__(16) float ws[64][64];   // [k][col]
    int br = blockIdx.x >> 2, bc = blockIdx.x & 3;
    int r0 = br * 64, c0 = bc * 64;
    int t = threadIdx.x;
    int lr = t >> 2, q = t & 3;
    int tc = (t & 15) * 4;
    int tr = (t >> 4) * 4;
    float acc[4][4] = {};

    for (int kt = 0; kt < 128; kt += 64) {
        int row = min(r0 + lr, N - 1);
        const float4* xrow = (const float4*)(X + (size_t)row * 128 + kt);
        const float4* wrow = (const float4*)(W + (size_t)(kt + lr) * 256 + c0);
        #pragma unroll
        for (int j = 0; j < 4; ++j) {
            int q4 = q + j * 4;
            float4 v = xrow[q4];
            xs[q4 * 4 + 0][lr] = v.x;
            xs[q4 * 4 + 1][lr] = v.y;
            xs[q4 * 4 + 2][lr] = v.z;
            xs[q4 * 4 + 3][lr] = v.w;
            float4 wvv = wrow[q4];
            *(float4*)&ws[lr][q4 * 4] = wvv;
        }
        __syncthreads();
        #pragma unroll 8
        for (int k = 0; k < 64; ++k) {
            float4 a = *(const float4*)&xs[k][tr];
            float4 b = *(const float4*)&ws[k][tc];
            float av[4] = {a.x, a.y, a.z, a.w};
            float bv[4] = {b.x, b.y, b.z, b.w};
            #pragma unroll
            for (int i = 0; i < 4; ++i)
                #pragma unroll
                for (int j = 0; j < 4; ++j)
                    acc[i][j] += av[i] * bv[j];
        }
        __syncthreads();
    }

    float4 bv4 = *(const float4*)(bias + c0 + tc);
    #pragma unroll
    for (int i = 0; i < 4; ++i) {
        int row = r0 + tr + i;
        if (row < N) {
            float4 o;
            o.x = acc[i][0] + bv4.x;
            o.y = acc[i][1] + bv4.y;
            o.z = acc[i][2] + bv4.z;
            o.w = acc[i][3] + bv4.w;
            *(float4*)(Y + (size_t)row * 256 + c0 + tc) = o;
            uint2 pk;
            pk.x = (unsigned)f2bf(o.x) | ((unsigned)f2bf(o.y) << 16);
            pk.y = (unsigned)f2bf(o.z) | ((unsigned)f2bf(o.w) << 16);
            Yb[(size_t)row * 64 + ((c0 + tc) >> 2)] = pk;
        }
    }
}

// ---------------------------------------------------------------------------
// Per-node attention logits
// ---------------------------------------------------------------------------

__global__ __launch_bounds__(256) void node_atts(const float* __restrict__ xh,
                                                 const float* __restrict__ att,
                                                 float* __restrict__ aiaj, int N) {
    int gt = blockIdx.x * blockDim.x + threadIdx.x;
    int wid = gt >> 6;
    int lane = threadIdx.x & 63;
    if (wid >= N) return;
    float4 xv = ((const float4*)xh)[(size_t)wid * 64 + lane];
    int head = lane >> 5;
    int dimbase = (lane & 31) * 4;
    const float* atth = att + head * (2 * DD + AA);
    float4 as = *(const float4*)(atth + dimbase);
    float4 ad = *(const float4*)(atth + DD + dimbase);
    float pi = xv.x * as.x + xv.y * as.y + xv.z * as.z + xv.w * as.w;
    float pj = xv.x * ad.x + xv.y * ad.y + xv.z * ad.z + xv.w * ad.w;
    #pragma unroll
    for (int o = 16; o; o >>= 1) {
        pi += __shfl_xor(pi, o);
        pj += __shfl_xor(pj, o);
    }
    float pi1 = __shfl(pi, 32);
    float pj1 = __shfl(pj, 32);
    if (lane == 0) {
        float4 r; r.x = pi; r.y = pi1; r.z = pj; r.w = pj1;
        ((float4*)aiaj)[wid] = r;
    }
}

// ---------------------------------------------------------------------------
// Fused edge transform for ALL 3 layers: edge evolution is independent of
// node features. One pass over edge_attr produces ae_perm for each layer,
// no intermediate e arrays.
// ---------------------------------------------------------------------------

__device__ inline void edge_stage(const float4& ev, const float* __restrict__ linE,
                                  const float* __restrict__ att, float2& ae, float4& enext) {
    float eh[8];
    #pragma unroll
    for (int c = 0; c < 8; ++c)
        eh[c] = ev.x * linE[c] + ev.y * linE[8 + c] + ev.z * linE[16 + c] + ev.w * linE[24 + c];
    float a0 = 0.f, a1 = 0.f;
    #pragma unroll
    for (int a = 0; a < 4; ++a) {
        a0 += eh[a]     * att[2 * DD + a];
        a1 += eh[4 + a] * att[(2 * DD + AA) + 2 * DD + a];
    }
    ae.x = a0; ae.y = a1;
    enext.x = fmaxf(0.5f * (eh[0] + eh[4]), 0.f);
    enext.y = fmaxf(0.5f * (eh[1] + eh[5]), 0.f);
    enext.z = fmaxf(0.5f * (eh[2] + eh[6]), 0.f);
    enext.w = fmaxf(0.5f * (eh[3] + eh[7]), 0.f);
}

__global__ __launch_bounds__(256) void edge_all(const float* __restrict__ ein,
                                                const float* __restrict__ linE0, const float* __restrict__ att0,
                                                const float* __restrict__ linE1, const float* __restrict__ att1,
                                                const float* __restrict__ linE2, const float* __restrict__ att2,
                                                const int* __restrict__ pos_of_edge,
                                                float2* __restrict__ ae0,
                                                float2* __restrict__ ae1,
                                                float2* __restrict__ ae2, int E) {
    int e = blockIdx.x * blockDim.x + threadIdx.x;
    if (e >= E) return;
    int p = pos_of_edge[e];
    float4 ev = ((const float4*)ein)[e];
    float2 ae; float4 en;
    edge_stage(ev, linE0, att0, ae, en); ae0[p] = ae;
    edge_stage(en, linE1, att1, ae, ev); ae1[p] = ae;
    edge_stage(ev, linE2, att2, ae, en); ae2[p] = ae;
}

// ---------------------------------------------------------------------------
// Aggregation: one wave per dst node; bf16 gather payload.
// Optionally fuses the final per-node dot with fw (last layer).
// ---------------------------------------------------------------------------

__global__ __launch_bounds__(64) void aggregate(const float* __restrict__ xh,
                                                const uint2* __restrict__ xhb,
                                                const float* __restrict__ aiaj,
                                                const float2* __restrict__ ae,
                                                const int* __restrict__ row_off,
                                                const int* __restrict__ csr_src,
                                                float* __restrict__ hout,
                                                const float* __restrict__ fw,
                                                float* __restrict__ pdots, int N) {
    int d = blockIdx.x;
    int lane = threadIdx.x;
    int s0 = row_off[d], s1 = row_off[d + 1];
    int deg = s1 - s0;
    const float2* aiaj2 = (const float2*)aiaj;
    float2 ajv = aiaj2[d * 2 + 1];   // (aj0, aj1)

    // Phase A: segment max per head
    float mx0 = -1e30f, mx1 = -1e30f;
    for (int i = lane; i < deg; i += 64) {
        int s = csr_src[s0 + i];
        float2 aiv = aiaj2[s * 2];
        float2 aev = ae[s0 + i];
        float a0 = aiv.x + ajv.x + aev.x; a0 = a0 > 0.f ? a0 : 0.2f * a0;
        float a1 = aiv.y + ajv.y + aev.y; a1 = a1 > 0.f ? a1 : 0.2f * a1;
        mx0 = fmaxf(mx0, a0); mx1 = fmaxf(mx1, a1);
    }
    #pragma unroll
    for (int o = 32; o; o >>= 1) {
        mx0 = fmaxf(mx0, __shfl_xor(mx0, o));
        mx1 = fmaxf(mx1, __shfl_xor(mx1, o));
    }

    __shared__ float lex[64][2];
    __shared__ int lsrc[64];
    float4 acc = {0.f, 0.f, 0.f, 0.f};
    float den0 = 0.f, den1 = 0.f;
    int head = lane >> 5;

    for (int c = 0; c < deg; c += 64) {
        int n = min(64, deg - c);
        if (lane < n) {
            int p = s0 + c + lane;
            int s = csr_src[p];
            float2 aiv = aiaj2[s * 2];
            float2 aev = ae[p];
            float a0 = aiv.x + ajv.x + aev.x; a0 = a0 > 0.f ? a0 : 0.2f * a0;
            float a1 = aiv.y + ajv.y + aev.y; a1 = a1 > 0.f ? a1 : 0.2f * a1;
            float e0 = __expf(a0 - mx0), e1 = __expf(a1 - mx1);
            den0 += e0; den1 += e1;
            lex[lane][0] = e0; lex[lane][1] = e1;
            lsrc[lane] = s;
        }
        __syncthreads();
        #pragma unroll 4
        for (int j = 0; j < n; ++j) {
            float w = lex[j][head];
            float4 xv = unpack_bf16x4(xhb[(size_t)lsrc[j] * 64 + lane]);
            acc.x += w * xv.x; acc.y += w * xv.y;
            acc.z += w * xv.z; acc.w += w * xv.w;
        }
        __syncthreads();
    }

    #pragma unroll
    for (int o = 32; o; o >>= 1) {
        den0 += __shfl_xor(den0, o);
        den1 += __shfl_xor(den1, o);
    }
    float den = head ? den1 : den0;
    if (deg == 0) den = 1.0f;
    float inv = 1.0f / den;

    float4 xd = ((const float4*)xh)[(size_t)d * 64 + lane];
    float4 v;
    v.x = acc.x * inv + xd.x;
    v.y = acc.y * inv + xd.y;
    v.z = acc.z * inv + xd.z;
    v.w = acc.w * inv + xd.w;
    float4 o2;
    o2.x = __shfl_xor(v.x, 32);
    o2.y = __shfl_xor(v.y, 32);
    o2.z = __shfl_xor(v.z, 32);
    o2.w = __shfl_xor(v.w, 32);
    if (lane < 32) {
        float4 r;
        r.x = fmaxf(0.5f * (v.x + o2.x), 0.f);
        r.y = fmaxf(0.5f * (v.y + o2.y), 0.f);
        r.z = fmaxf(0.5f * (v.z + o2.z), 0.f);
        r.w = fmaxf(0.5f * (v.w + o2.w), 0.f);
        ((float4*)hout)[(size_t)d * 32 + lane] = r;
        if (pdots) {
            float4 wv = ((const float4*)fw)[lane];
            float pd = r.x * wv.x + r.y * wv.y + r.z * wv.z + r.w * wv.w;
            #pragma unroll
            for (int o = 16; o; o >>= 1) pd += __shfl_xor(pd, o);
            if (lane == 0) pdots[d] = pd;
        }
    }
}

// ---------------------------------------------------------------------------
// Final pooling: segment-sum of per-node dots (batch is sorted)
// ---------------------------------------------------------------------------

__global__ __launch_bounds__(256) void segpool_kernel(const float* __restrict__ p,
                                                      const int* __restrict__ batch,
                                                      float* __restrict__ y, int N, int G) {
    __shared__ float bins[128];
    int t = threadIdx.x;
    if (t < G) bins[t] = 0.f;
    __syncthreads();
    int per = (N + gridDim.x - 1) / gridDim.x;
    int lo = blockIdx.x * per;
    int hi = min(lo + per, N);
    float acc = 0.f;
    int key = -1;
    for (int i = lo + t; i < hi; i += 256) {
        int k = batch[i];
        float v = p[i];
        if (k != key) {
            if (key >= 0) atomicAdd(&bins[key], acc);
            key = k;
            acc = 0.f;
        }
        acc += v;
    }
    if (key >= 0) atomicAdd(&bins[key], acc);
    __syncthreads();
    if (t < G && bins[t] != 0.f) atomicAdd(&y[t], bins[t]);
}

__global__ void init_y(float* __restrict__ y, const float* __restrict__ fb, int G) {
    int g = blockIdx.x * blockDim.x + threadIdx.x;
    if (g < G) y[g] = fb[0];
}

// ---------------------------------------------------------------------------
// Host side
// ---------------------------------------------------------------------------

extern "C" void kernel_launch(void* const* d_in, const int* in_sizes, int n_in,
                              void* d_out, int out_size, void* d_ws, size_t ws_size,
                              hipStream_t stream) {
    const float* x     = (const float*)d_in[0];
    const int*   ei    = (const int*)d_in[1];
    const float* eattr = (const float*)d_in[2];
    const int*   batch = (const int*)d_in[3];
    const float* fw    = (const float*)d_in[16];
    const float* fb    = (const float*)d_in[17];
    float* y = (float*)d_out;

    const int N = in_sizes[0] / DD;     // 50000
    const int E = in_sizes[1] / 2;      // 800000
    const int G = out_size;             // 128

    const int* src = ei;
    const int* dst = ei + E;

    char* ws = (char*)d_ws;
    size_t off = 0;
    auto carve = [&](size_t bytes) {
        char* p = ws + off;
        off += (bytes + 255) & ~(size_t)255;
        return p;
    };
    float*  xh      = (float*)carve((size_t)N * 256 * 4);
    uint2*  xhb     = (uint2*)carve((size_t)N * 256 * 2);   // bf16 copy
    float*  hA      = (float*)carve((size_t)N * 128 * 4);
    float*  hB      = (float*)carve((size_t)N * 128 * 4);
    float2* ae0     = (float2*)carve((size_t)E * 2 * 4);
    float2* ae1     = (float2*)carve((size_t)E * 2 * 4);
    float2* ae2     = (float2*)carve((size_t)E * 2 * 4);
    float*  aiaj    = (float*)carve((size_t)N * 4 * 4);
    int*    row_off = (int*)carve((size_t)(N + 1) * 4);
    int*    cursor  = (int*)carve((size_t)N * 4);
    int*    cnt     = (int*)carve((size_t)N * 4);
    int*    csr_src = (int*)carve((size_t)E * 4);
    int*    pos     = (int*)carve((size_t)E * 4);
    float*  pdots   = (float*)carve((size_t)N * 4);
    int*    bsum    = (int*)carve((size_t)256 * 4);

    const int NB = (N + 1023) / 1024;   // scan chunks (49 <= 64)

    // ---- CSR build ----
    hipMemsetAsync(cnt, 0, (size_t)N * 4, stream);
    int eb = (E + 255) / 256;
    hist_kernel<<<eb, 256, 0, stream>>>(dst, cnt, E);
    scan1<<<NB, 256, 0, stream>>>(cnt, bsum, N);
    scan2<<<1, 64, 0, stream>>>(bsum, NB, row_off + N);
    scan3<<<NB, 256, 0, stream>>>(cnt, bsum, row_off, cursor, N);
    scatter_kernel<<<eb, 256, 0, stream>>>(src, dst, cursor, csr_src, pos, E);

    // ---- all-layer edge transform (independent of node features) ----
    edge_all<<<eb, 256, 0, stream>>>(eattr,
                                     (const float*)d_in[5], (const float*)d_in[6],
                                     (const float*)d_in[9], (const float*)d_in[10],
                                     (const float*)d_in[13], (const float*)d_in[14],
                                     pos, ae0, ae1, ae2, E);

    // ---- 3 GAT layers ----
    const float* xin = x;
    int gemm_blocks = ((N + 63) / 64) * 4;
    int wave_blocks = (N * 64 + 255) / 256;
    float2* aes[3] = {ae0, ae1, ae2};

    for (int l = 0; l < 3; ++l) {
        const float* linN = (const float*)d_in[4 + 4 * l];
        const float* att  = (const float*)d_in[6 + 4 * l];
        const float* bias = (const float*)d_in[7 + 4 * l];
        float* hout = (l == 0) ? hA : (l == 1) ? hB : hA;

        gemm_xh<<<gemm_blocks, 256, 0, stream>>>(xin, linN, bias, xh, xhb, N);
        node_atts<<<wave_blocks, 256, 0, stream>>>(xh, att, aiaj, N);
        aggregate<<<N, 64, 0, stream>>>(xh, xhb, aiaj, aes[l], row_off, csr_src, hout,
                                        fw, (l == 2) ? pdots : nullptr, N);
        xin = hout;
    }

    // ---- pooling ----
    init_y<<<1, 128, 0, stream>>>(y, fb, G);
    segpool_kernel<<<128, 256, 0, stream>>>(pdots, batch, y, N, G);
}